// Round 1
// baseline (223.066 us; speedup 1.0000x reference)
//
#include <hip/hip_runtime.h>
#include <stdint.h>

#define LOG2E 1.44269504088896340736f
#define QSCALE (0.125f * LOG2E)   // dim_head^-0.5 folded with log2(e) for exp2-domain softmax

typedef __bf16 bf16x8 __attribute__((ext_vector_type(8)));
typedef float floatx4 __attribute__((ext_vector_type(4)));

__device__ __forceinline__ unsigned short f2b(float f) {
  union { float f; unsigned int u; } v; v.f = f;
  unsigned int u = v.u;
  return (unsigned short)((u + 0x7fffu + ((u >> 16) & 1u)) >> 16);  // RNE
}

__device__ __forceinline__ void gl2lds16(const void* g, void* l) {
  __builtin_amdgcn_global_load_lds((const __attribute__((address_space(1))) void*)g,
                                   (__attribute__((address_space(3))) void*)l, 16, 0, 0);
}

// ---------------- elementwise fp32 -> bf16 ----------------
__global__ __launch_bounds__(256) void cvt_f32_bf16(const float* __restrict__ in,
                                                    unsigned short* __restrict__ out, int n) {
  int i = (blockIdx.x * 256 + threadIdx.x) * 4;
  if (i >= n) return;
  float4 v = *(const float4*)(in + i);
  unsigned long long pk = (unsigned long long)f2b(v.x)
                        | ((unsigned long long)f2b(v.y) << 16)
                        | ((unsigned long long)f2b(v.z) << 32)
                        | ((unsigned long long)f2b(v.w) << 48);
  *(unsigned long long*)(out + i) = pk;
}

// ---------------- transpose + convert: in[K][N] fp32 -> out[N][K] bf16 ----------------
__global__ __launch_bounds__(256) void transpose_cvt(const float* __restrict__ in,
                                                     unsigned short* __restrict__ out,
                                                     int K, int N) {
  __shared__ float tile[32][33];
  int k0 = blockIdx.y * 32, n0 = blockIdx.x * 32;
#pragma unroll
  for (int r = threadIdx.y; r < 32; r += 8)
    tile[r][threadIdx.x] = in[(long)(k0 + r) * N + n0 + threadIdx.x];
  __syncthreads();
#pragma unroll
  for (int r = threadIdx.y; r < 32; r += 8)
    out[(long)(n0 + r) * K + k0 + threadIdx.x] = f2b(tile[threadIdx.x][r]);
}

// ---------------- bf16 GEMM: C[M,N] = A[M,K] * Bt[N,K]^T, 128x128x32 tiles ----------------
// EPI 0: Q epilogue  -> outA = Qb[b,h,n,d] bf16, scaled by QSCALE
// EPI 1: KV epilogue -> outA = Kb[b,h,m,d] bf16 (cols<512), outB = Vt[b,h,d,m] bf16 (cols>=512)
// EPI 2: final       -> outF = fp32 [M,N] + bias[col]
template <int EPI>
__global__ __launch_bounds__(256)
void gemm_bf16(const unsigned short* __restrict__ A,
               const unsigned short* __restrict__ Bt,
               unsigned short* __restrict__ outA,
               unsigned short* __restrict__ outB,
               float* __restrict__ outF,
               const float* __restrict__ bias,
               int M, int N, int K)
{
  __shared__ unsigned short As[128 * 32];
  __shared__ unsigned short Bs[128 * 32];

  const int tid = threadIdx.x;
  const int wave = tid >> 6;
  const int lane = tid & 63;
  const int l15 = lane & 15;
  const int q4 = lane >> 4;
  const int wm = (wave & 1) * 64;
  const int wn = (wave >> 1) * 64;
  const long bm = (long)blockIdx.y * 128;
  const long bn = (long)blockIdx.x * 128;

  floatx4 acc[4][4];
#pragma unroll
  for (int i = 0; i < 4; ++i)
#pragma unroll
    for (int j = 0; j < 4; ++j) { acc[i][j][0]=0.f; acc[i][j][1]=0.f; acc[i][j][2]=0.f; acc[i][j][3]=0.f; }

  for (int k0 = 0; k0 < K; k0 += 32) {
#pragma unroll
    for (int cc = 0; cc < 2; ++cc) {
      int c = cc * 256 + tid;
      int r = c >> 2, kc = c & 3;
      gl2lds16(A  + (bm + r) * (long)K + k0 + kc * 8, (char*)As + c * 16);
      gl2lds16(Bt + (bn + r) * (long)K + k0 + kc * 8, (char*)Bs + c * 16);
    }
    __syncthreads();
    bf16x8 af[4], bfr[4];
#pragma unroll
    for (int i = 0; i < 4; ++i)
      af[i] = *(const bf16x8*)(As + (wm + i * 16 + l15) * 32 + q4 * 8);
#pragma unroll
    for (int j = 0; j < 4; ++j)
      bfr[j] = *(const bf16x8*)(Bs + (wn + j * 16 + l15) * 32 + q4 * 8);
#pragma unroll
    for (int i = 0; i < 4; ++i)
#pragma unroll
      for (int j = 0; j < 4; ++j)
        acc[i][j] = __builtin_amdgcn_mfma_f32_16x16x32_bf16(af[i], bfr[j], acc[i][j], 0, 0, 0);
    __syncthreads();
  }

#pragma unroll
  for (int i = 0; i < 4; ++i) {
#pragma unroll
    for (int j = 0; j < 4; ++j) {
#pragma unroll
      for (int r = 0; r < 4; ++r) {
        long row = bm + wm + i * 16 + q4 * 4 + r;   // C/D layout: row=(lane>>4)*4+reg, col=lane&15
        long col = bn + wn + j * 16 + l15;
        float v = acc[i][j][r];
        if (EPI == 0) {
          long b = row >> 10, n = row & 1023;
          long h = col >> 6, d = col & 63;
          outA[((b * 8 + h) * 1024 + n) * 64 + d] = f2b(v * QSCALE);
        } else if (EPI == 1) {
          long b = row >> 10, m = row & 1023;
          long d = col & 63;
          if (col < 512) {
            long h = col >> 6;
            outA[((b * 8 + h) * 1024 + m) * 64 + d] = f2b(v);
          } else {
            long h = (col - 512) >> 6;
            outB[((b * 8 + h) * 64 + d) * 1024 + m] = f2b(v);
          }
        } else {
          outF[row * (long)N + col] = v + bias[col];
        }
      }
    }
  }
}

// ---------------- flash attention ----------------
// grid (64 bh, 8 nblk), 256 threads. Each wave: 32 q-rows. KV tiles of 64.
__global__ __launch_bounds__(256)
void attn_kernel(const unsigned short* __restrict__ Qb,  // [64][1024][64] (pre-scaled)
                 const unsigned short* __restrict__ Kb,  // [64][1024][64]
                 const unsigned short* __restrict__ Vt,  // [64][64][1024]
                 unsigned short* __restrict__ Ob)        // [8192][512]
{
  __shared__ unsigned short Ksm[2][4096];
  __shared__ unsigned short Vsm[2][4096];
  __shared__ unsigned short Psm[128 * 64];

  const int tid = threadIdx.x;
  const int wave = tid >> 6;
  const int lane = tid & 63;
  const int l15 = lane & 15;
  const int q4 = lane >> 4;
  const int bh = blockIdx.x;
  const int nb = blockIdx.y;

  const long qrow0 = (long)bh * 1024 + nb * 128 + wave * 32;

  // Q A-frags in registers: A[m=lane&15][k=(lane>>4)*8+j]
  bf16x8 qf[2][2];
#pragma unroll
  for (int i = 0; i < 2; ++i)
#pragma unroll
    for (int ks = 0; ks < 2; ++ks)
      qf[i][ks] = *(const bf16x8*)(Qb + (qrow0 + i * 16 + l15) * 64 + ks * 32 + q4 * 8);

  floatx4 acc[2][4];
#pragma unroll
  for (int i = 0; i < 2; ++i)
#pragma unroll
    for (int d = 0; d < 4; ++d) { acc[i][d][0]=0.f; acc[i][d][1]=0.f; acc[i][d][2]=0.f; acc[i][d][3]=0.f; }
  float mrun[2][4], lrun[2][4];
#pragma unroll
  for (int i = 0; i < 2; ++i)
#pragma unroll
    for (int r = 0; r < 4; ++r) { mrun[i][r] = -1e30f; lrun[i][r] = 0.0f; }

  // stage tile 0 (XOR-swizzled 16B chunks: rows are 128B => unswizzled is bank-degenerate)
#pragma unroll
  for (int cc = 0; cc < 2; ++cc) {
    int c = cc * 256 + tid;
    int jrow = c >> 3, csw = c & 7;
    int cact = csw ^ (jrow & 7);
    gl2lds16(Kb + ((long)bh * 1024 + jrow) * 64 + cact * 8, (char*)Ksm[0] + c * 16);
    gl2lds16(Vt + ((long)bh * 64 + jrow) * 1024 + cact * 8, (char*)Vsm[0] + c * 16);
  }

  for (int t = 0; t < 16; ++t) {
    __syncthreads();              // drains stage(t); all waves done reading buf[(t+1)&1]
    const int cur = t & 1;
    if (t + 1 < 16) {
      const int nxt = cur ^ 1;
#pragma unroll
      for (int cc = 0; cc < 2; ++cc) {
        int c = cc * 256 + tid;
        int jrow = c >> 3, csw = c & 7;
        int cact = csw ^ (jrow & 7);
        gl2lds16(Kb + ((long)bh * 1024 + (t + 1) * 64 + jrow) * 64 + cact * 8, (char*)Ksm[nxt] + c * 16);
        gl2lds16(Vt + ((long)bh * 64 + jrow) * 1024 + (t + 1) * 64 + cact * 8, (char*)Vsm[nxt] + c * 16);
      }
    }

    // S = Q K^T (exp2-domain, scale pre-folded into Q)
    floatx4 s[2][4];
#pragma unroll
    for (int i = 0; i < 2; ++i)
#pragma unroll
      for (int j = 0; j < 4; ++j) { s[i][j][0]=0.f; s[i][j][1]=0.f; s[i][j][2]=0.f; s[i][j][3]=0.f; }
#pragma unroll
    for (int ks = 0; ks < 2; ++ks) {
      bf16x8 kfr[4];
#pragma unroll
      for (int jn = 0; jn < 4; ++jn) {
        int j = jn * 16 + l15;
        int cact = (ks * 4 + q4) ^ (j & 7);
        kfr[jn] = *(const bf16x8*)(Ksm[cur] + j * 64 + cact * 8);
      }
#pragma unroll
      for (int i = 0; i < 2; ++i)
#pragma unroll
        for (int jn = 0; jn < 4; ++jn)
          s[i][jn] = __builtin_amdgcn_mfma_f32_16x16x32_bf16(qf[i][ks], kfr[jn], s[i][jn], 0, 0, 0);
    }

    // online softmax + P -> LDS (swizzled, wave-private rows)
#pragma unroll
    for (int i = 0; i < 2; ++i) {
      float al[4];
#pragma unroll
      for (int r = 0; r < 4; ++r) {
        float tm = fmaxf(fmaxf(s[i][0][r], s[i][1][r]), fmaxf(s[i][2][r], s[i][3][r]));
#pragma unroll
        for (int off = 8; off >= 1; off >>= 1)
          tm = fmaxf(tm, __shfl_xor(tm, off, 64));
        float mnew = fmaxf(mrun[i][r], tm);
        float alpha = exp2f(mrun[i][r] - mnew);
        mrun[i][r] = mnew;
        float rs = 0.0f;
#pragma unroll
        for (int jn = 0; jn < 4; ++jn) {
          float p = exp2f(s[i][jn][r] - mnew);
          s[i][jn][r] = p;
          rs += p;
        }
#pragma unroll
        for (int off = 8; off >= 1; off >>= 1)
          rs += __shfl_xor(rs, off, 64);
        lrun[i][r] = lrun[i][r] * alpha + rs;
        al[r] = alpha;
      }
#pragma unroll
      for (int d = 0; d < 4; ++d)
#pragma unroll
        for (int r = 0; r < 4; ++r)
          acc[i][d][r] *= al[r];
#pragma unroll
      for (int jn = 0; jn < 4; ++jn) {
        int colbase = jn * 16 + l15;
#pragma unroll
        for (int r = 0; r < 4; ++r) {
          int row = wave * 32 + i * 16 + q4 * 4 + r;
          int idx = row * 64 + (((colbase >> 3) ^ (row & 7)) << 3) + (colbase & 7);
          Psm[idx] = f2b(s[i][jn][r]);
        }
      }
    }
    __asm__ volatile("s_waitcnt lgkmcnt(0)" ::: "memory");

    // O += P * V  (A-frag from Psm, B-frag from Vsm — both swizzle-matched)
#pragma unroll
    for (int ks = 0; ks < 2; ++ks) {
      bf16x8 pa[2], vb[4];
#pragma unroll
      for (int i = 0; i < 2; ++i) {
        int m = wave * 32 + i * 16 + l15;
        int cact = (ks * 4 + q4) ^ (m & 7);
        pa[i] = *(const bf16x8*)(Psm + m * 64 + cact * 8);
      }
#pragma unroll
      for (int dn = 0; dn < 4; ++dn) {
        int dd = dn * 16 + l15;
        int cact = (ks * 4 + q4) ^ (dd & 7);
        vb[dn] = *(const bf16x8*)(Vsm[cur] + dd * 64 + cact * 8);
      }
#pragma unroll
      for (int i = 0; i < 2; ++i)
#pragma unroll
        for (int dn = 0; dn < 4; ++dn)
          acc[i][dn] = __builtin_amdgcn_mfma_f32_16x16x32_bf16(pa[i], vb[dn], acc[i][dn], 0, 0, 0);
    }
  }

  // epilogue: O /= l, write bf16 into [B*N][H*64] layout for final GEMM
  const int b = bh >> 3, h = bh & 7;
#pragma unroll
  for (int i = 0; i < 2; ++i) {
    float inv[4];
#pragma unroll
    for (int r = 0; r < 4; ++r) inv[r] = 1.0f / lrun[i][r];
#pragma unroll
    for (int dn = 0; dn < 4; ++dn) {
#pragma unroll
      for (int r = 0; r < 4; ++r) {
        long row = (long)b * 1024 + nb * 128 + wave * 32 + i * 16 + q4 * 4 + r;
        long col = h * 64 + dn * 16 + l15;
        Ob[row * 512 + col] = f2b(acc[i][dn][r] * inv[r]);
      }
    }
  }
}

extern "C" void kernel_launch(void* const* d_in, const int* in_sizes, int n_in,
                              void* d_out, int out_size, void* d_ws, size_t ws_size,
                              hipStream_t stream) {
  const float* x   = (const float*)d_in[0];   // [8,1024,512]
  const float* ctx = (const float*)d_in[1];   // [8,1024,512]
  const float* Wq  = (const float*)d_in[2];   // [512,512]
  const float* Wkv = (const float*)d_in[3];   // [512,1024]
  const float* Wo  = (const float*)d_in[4];   // [512,512]
  const float* bo  = (const float*)d_in[5];   // [512]
  float* out = (float*)d_out;

  char* ws = (char*)d_ws;
  unsigned short* Xb   = (unsigned short*)(ws);                 // 8 MB
  unsigned short* Cb   = (unsigned short*)(ws + (8u  << 20));   // 8 MB
  unsigned short* WqT  = (unsigned short*)(ws + (16u << 20));   // 0.5 MB
  unsigned short* WkvT = (unsigned short*)(ws + (17u << 20));   // 1 MB
  unsigned short* WoT  = (unsigned short*)(ws + (19u << 20));   // 0.5 MB
  unsigned short* Qb   = (unsigned short*)(ws + (20u << 20));   // 8 MB
  unsigned short* Kb   = (unsigned short*)(ws + (28u << 20));   // 8 MB
  unsigned short* Vt   = (unsigned short*)(ws + (36u << 20));   // 8 MB
  unsigned short* Ob   = (unsigned short*)(ws + (44u << 20));   // 8 MB  (total 52 MB)

  cvt_f32_bf16<<<4096, 256, 0, stream>>>(x,   Xb, 8 * 1024 * 512);
  cvt_f32_bf16<<<4096, 256, 0, stream>>>(ctx, Cb, 8 * 1024 * 512);
  transpose_cvt<<<dim3(16, 16), dim3(32, 8), 0, stream>>>(Wq,  WqT,  512, 512);
  transpose_cvt<<<dim3(32, 16), dim3(32, 8), 0, stream>>>(Wkv, WkvT, 512, 1024);
  transpose_cvt<<<dim3(16, 16), dim3(32, 8), 0, stream>>>(Wo,  WoT,  512, 512);

  gemm_bf16<0><<<dim3(4, 64), 256, 0, stream>>>(Xb, WqT, Qb, nullptr, nullptr, nullptr, 8192, 512, 512);
  gemm_bf16<1><<<dim3(8, 64), 256, 0, stream>>>(Cb, WkvT, Kb, Vt, nullptr, nullptr, 8192, 1024, 512);
  attn_kernel<<<dim3(64, 8), 256, 0, stream>>>(Qb, Kb, Vt, Ob);
  gemm_bf16<2><<<dim3(4, 64), 256, 0, stream>>>(Ob, WoT, nullptr, nullptr, out, bo, 8192, 512, 512);
}

// Round 2
// 174.007 us; speedup vs baseline: 1.2819x; 1.2819x over previous
//
#include <hip/hip_runtime.h>
#include <stdint.h>

#define LOG2E 1.44269504088896340736f
#define QSCALE (0.125f * LOG2E)   // dim_head^-0.5 folded with log2(e) for exp2-domain softmax

typedef __bf16 bf16x8 __attribute__((ext_vector_type(8)));
typedef float floatx4 __attribute__((ext_vector_type(4)));

__device__ __forceinline__ unsigned short bfbits(float f) {
  __bf16 h = (__bf16)f;                       // v_cvt_pk_bf16_f32 (RNE)
  return __builtin_bit_cast(unsigned short, h);
}

__device__ __forceinline__ float fast_exp2(float x) {
#if __has_builtin(__builtin_amdgcn_exp2f)
  return __builtin_amdgcn_exp2f(x);
#else
  return exp2f(x);
#endif
}

__device__ __forceinline__ void gl2lds16(const void* g, void* l) {
  __builtin_amdgcn_global_load_lds((const __attribute__((address_space(1))) void*)g,
                                   (__attribute__((address_space(3))) void*)l, 16, 0, 0);
}

// ---------------- fused fp32 -> bf16 for x and context ----------------
__global__ __launch_bounds__(256) void cvt2_f32_bf16(const float* __restrict__ a,
                                                     const float* __restrict__ b,
                                                     unsigned short* __restrict__ oa,
                                                     unsigned short* __restrict__ ob) {
  int blk = blockIdx.x;
  const float* in = blk < 4096 ? a : b;
  unsigned short* out = blk < 4096 ? oa : ob;
  int i = (((blk & 4095) * 256) + threadIdx.x) * 4;
  float4 v = *(const float4*)(in + i);
  unsigned long long pk = (unsigned long long)bfbits(v.x)
                        | ((unsigned long long)bfbits(v.y) << 16)
                        | ((unsigned long long)bfbits(v.z) << 32)
                        | ((unsigned long long)bfbits(v.w) << 48);
  *(unsigned long long*)(out + i) = pk;
}

// ---------------- fused transpose+convert for Wq/Wkv/Wo: in[512][N] -> out[N][512] ----------------
__global__ __launch_bounds__(256) void transpose_cvt3(const float* __restrict__ w0,
                                                      const float* __restrict__ w1,
                                                      const float* __restrict__ w2,
                                                      unsigned short* __restrict__ o0,
                                                      unsigned short* __restrict__ o1,
                                                      unsigned short* __restrict__ o2) {
  __shared__ float tile[32][33];
  int z = blockIdx.z;
  const float* in = (z == 0) ? w0 : ((z == 1) ? w1 : w2);
  unsigned short* out = (z == 0) ? o0 : ((z == 1) ? o1 : o2);
  const int N = (z == 1) ? 1024 : 512;
  if (blockIdx.x * 32 >= N) return;
  const int K = 512;
  int k0 = blockIdx.y * 32, n0 = blockIdx.x * 32;
#pragma unroll
  for (int r = threadIdx.y; r < 32; r += 8)
    tile[r][threadIdx.x] = in[(long)(k0 + r) * N + n0 + threadIdx.x];
  __syncthreads();
#pragma unroll
  for (int r = threadIdx.y; r < 32; r += 8)
    out[(long)(n0 + r) * K + k0 + threadIdx.x] = bfbits(tile[threadIdx.x][r]);
}

// ---------------- bf16 GEMM: C[M,N] = A[M,K] * Bt[N,K]^T, BMx128x32 tiles ----------------
// EPI 0: Q  -> outA = Qb[b,h,n,d] bf16, scaled by QSCALE
// EPI 1: KV -> outA = Kb[b,h,m,d] bf16 (cols<512), outB = Vt[b,h,d,m] bf16 (cols>=512, 8B packed)
// EPI 2: final -> outF = fp32 [M,N] + bias[col]
template <int EPI, int BM>
__global__ __launch_bounds__(256)
void gemm_bf16(const unsigned short* __restrict__ A,
               const unsigned short* __restrict__ Bt,
               unsigned short* __restrict__ outA,
               unsigned short* __restrict__ outB,
               float* __restrict__ outF,
               const float* __restrict__ bias,
               int M, int N, int K)
{
  constexpr int IC = BM / 32;   // 16-row A-frags per wave
  __shared__ unsigned short As[BM * 32];
  __shared__ unsigned short Bs[128 * 32];

  const int tid = threadIdx.x;
  const int wave = tid >> 6;
  const int lane = tid & 63;
  const int l15 = lane & 15;
  const int q4 = lane >> 4;
  const int wm = (wave & 1) * (BM / 2);
  const int wn = (wave >> 1) * 64;
  const long bm = (long)blockIdx.y * BM;
  const long bn = (long)blockIdx.x * 128;

  floatx4 acc[IC][4];
#pragma unroll
  for (int i = 0; i < IC; ++i)
#pragma unroll
    for (int j = 0; j < 4; ++j) { acc[i][j][0]=0.f; acc[i][j][1]=0.f; acc[i][j][2]=0.f; acc[i][j][3]=0.f; }

  for (int k0 = 0; k0 < K; k0 += 32) {
#pragma unroll
    for (int cc = 0; cc < BM / 64; ++cc) {
      int c = cc * 256 + tid;
      int r = c >> 2, kc = c & 3;
      gl2lds16(A + (bm + r) * (long)K + k0 + kc * 8, (char*)As + c * 16);
    }
#pragma unroll
    for (int cc = 0; cc < 2; ++cc) {
      int c = cc * 256 + tid;
      int r = c >> 2, kc = c & 3;
      gl2lds16(Bt + (bn + r) * (long)K + k0 + kc * 8, (char*)Bs + c * 16);
    }
    __syncthreads();
    bf16x8 af[IC], bfr[4];
#pragma unroll
    for (int i = 0; i < IC; ++i)
      af[i] = *(const bf16x8*)(As + (wm + i * 16 + l15) * 32 + q4 * 8);
#pragma unroll
    for (int j = 0; j < 4; ++j)
      bfr[j] = *(const bf16x8*)(Bs + (wn + j * 16 + l15) * 32 + q4 * 8);
#pragma unroll
    for (int i = 0; i < IC; ++i)
#pragma unroll
      for (int j = 0; j < 4; ++j)
        acc[i][j] = __builtin_amdgcn_mfma_f32_16x16x32_bf16(af[i], bfr[j], acc[i][j], 0, 0, 0);
    __syncthreads();
  }

#pragma unroll
  for (int i = 0; i < IC; ++i) {
#pragma unroll
    for (int j = 0; j < 4; ++j) {
      long col = bn + wn + j * 16 + l15;
      if (EPI == 1 && bn >= 512) {
        // V half: pack 4 consecutive-m bf16 into one 8B store (Vt[b,h,d,m])
        long h = (col - 512) >> 6, d = col & 63;
        long row0 = bm + wm + i * 16 + q4 * 4;
        long b = row0 >> 10, m0 = row0 & 1023;
        unsigned long long pk = (unsigned long long)bfbits(acc[i][j][0])
                              | ((unsigned long long)bfbits(acc[i][j][1]) << 16)
                              | ((unsigned long long)bfbits(acc[i][j][2]) << 32)
                              | ((unsigned long long)bfbits(acc[i][j][3]) << 48);
        *(unsigned long long*)(outB + ((b * 8 + h) * 64 + d) * 1024 + m0) = pk;
      } else {
#pragma unroll
        for (int r = 0; r < 4; ++r) {
          long row = bm + wm + i * 16 + q4 * 4 + r;   // C/D: row=(lane>>4)*4+reg, col=lane&15
          float v = acc[i][j][r];
          if (EPI == 0) {
            long b = row >> 10, n = row & 1023;
            long h = col >> 6, d = col & 63;
            outA[((b * 8 + h) * 1024 + n) * 64 + d] = bfbits(v * QSCALE);
          } else if (EPI == 1) {
            long b = row >> 10, m = row & 1023;
            long h = col >> 6, d = col & 63;
            outA[((b * 8 + h) * 1024 + m) * 64 + d] = bfbits(v);
          } else {
            outF[row * (long)N + col] = v + bias[col];
          }
        }
      }
    }
  }
}

// ---------------- flash attention (no-max exp2 softmax, deferred sum) ----------------
// grid (64 bh, 8 nblk), 256 threads. Each wave: 32 q-rows. KV tiles of 64.
__global__ __launch_bounds__(256)
void attn_kernel(const unsigned short* __restrict__ Qb,  // [64][1024][64] (pre-scaled)
                 const unsigned short* __restrict__ Kb,  // [64][1024][64]
                 const unsigned short* __restrict__ Vt,  // [64][64][1024]
                 unsigned short* __restrict__ Ob)        // [8192][512]
{
  __shared__ unsigned short Ksm[2][4096];
  __shared__ unsigned short Vsm[2][4096];
  __shared__ unsigned short Psm[128 * 64];

  const int tid = threadIdx.x;
  const int wave = tid >> 6;
  const int lane = tid & 63;
  const int l15 = lane & 15;
  const int q4 = lane >> 4;
  const int bh = blockIdx.x;
  const int nb = blockIdx.y;

  const long qrow0 = (long)bh * 1024 + nb * 128 + wave * 32;

  // Q A-frags in registers: A[m=lane&15][k=(lane>>4)*8+j]
  bf16x8 qf[2][2];
#pragma unroll
  for (int i = 0; i < 2; ++i)
#pragma unroll
    for (int ks = 0; ks < 2; ++ks)
      qf[i][ks] = *(const bf16x8*)(Qb + (qrow0 + i * 16 + l15) * 64 + ks * 32 + q4 * 8);

  floatx4 acc[2][4];
#pragma unroll
  for (int i = 0; i < 2; ++i)
#pragma unroll
    for (int d = 0; d < 4; ++d) { acc[i][d][0]=0.f; acc[i][d][1]=0.f; acc[i][d][2]=0.f; acc[i][d][3]=0.f; }
  float suml[2][4];
#pragma unroll
  for (int i = 0; i < 2; ++i)
#pragma unroll
    for (int r = 0; r < 4; ++r) suml[i][r] = 0.0f;

  // staging offsets (XOR-swizzled 16B chunks; rows are 128B => unswizzled is bank-degenerate)
  const unsigned short* Kbase = Kb + (long)bh * 65536;
  const unsigned short* Vbase = Vt + (long)bh * 65536;
  int koff[2], voff[2], lds16[2];
#pragma unroll
  for (int cc = 0; cc < 2; ++cc) {
    int c = cc * 256 + tid;
    int jrow = c >> 3;
    int cact = (c & 7) ^ (jrow & 7);
    koff[cc] = jrow * 64 + cact * 8;     // within K tile (64 rows x 64 d)
    voff[cc] = jrow * 1024 + cact * 8;   // within V (64 d-rows x 1024 m), tile adds +64*t
    lds16[cc] = c * 16;                  // byte offset in LDS buffer
  }

#pragma unroll
  for (int cc = 0; cc < 2; ++cc) {
    gl2lds16(Kbase + koff[cc], (char*)Ksm[0] + lds16[cc]);
    gl2lds16(Vbase + voff[cc], (char*)Vsm[0] + lds16[cc]);
  }

  for (int t = 0; t < 16; ++t) {
    __syncthreads();              // drains stage(t); all waves done reading buf[(t+1)&1]
    const int cur = t & 1;
    if (t + 1 < 16) {
      const int nxt = cur ^ 1;
#pragma unroll
      for (int cc = 0; cc < 2; ++cc) {
        gl2lds16(Kbase + (t + 1) * 4096 + koff[cc], (char*)Ksm[nxt] + lds16[cc]);
        gl2lds16(Vbase + (t + 1) * 64 + voff[cc], (char*)Vsm[nxt] + lds16[cc]);
      }
    }

    // S = Q K^T (exp2-domain, scale pre-folded into Q)
    floatx4 s[2][4];
#pragma unroll
    for (int i = 0; i < 2; ++i)
#pragma unroll
      for (int j = 0; j < 4; ++j) { s[i][j][0]=0.f; s[i][j][1]=0.f; s[i][j][2]=0.f; s[i][j][3]=0.f; }
#pragma unroll
    for (int ks = 0; ks < 2; ++ks) {
      bf16x8 kfr[4];
#pragma unroll
      for (int jn = 0; jn < 4; ++jn) {
        int j = jn * 16 + l15;
        int cact = (ks * 4 + q4) ^ (j & 7);
        kfr[jn] = *(const bf16x8*)(Ksm[cur] + j * 64 + cact * 8);
      }
#pragma unroll
      for (int i = 0; i < 2; ++i)
#pragma unroll
        for (int jn = 0; jn < 4; ++jn)
          s[i][jn] = __builtin_amdgcn_mfma_f32_16x16x32_bf16(qf[i][ks], kfr[jn], s[i][jn], 0, 0, 0);
    }

    // p = exp2(s); accumulate per-lane row sums; P -> LDS (swizzled, wave-private rows)
#pragma unroll
    for (int i = 0; i < 2; ++i) {
#pragma unroll
      for (int jn = 0; jn < 4; ++jn) {
        int colbase = jn * 16 + l15;
#pragma unroll
        for (int r = 0; r < 4; ++r) {
          float p = fast_exp2(s[i][jn][r]);
          suml[i][r] += p;
          int row = wave * 32 + i * 16 + q4 * 4 + r;
          int idx = row * 64 + (((colbase >> 3) ^ (row & 7)) << 3) + (colbase & 7);
          ((__bf16*)Psm)[idx] = (__bf16)p;
        }
      }
    }
    __asm__ volatile("s_waitcnt lgkmcnt(0)" ::: "memory");

    // O += P * V  (A-frag from Psm, B-frag from Vsm — both swizzle-matched)
#pragma unroll
    for (int ks = 0; ks < 2; ++ks) {
      bf16x8 pa[2], vb[4];
#pragma unroll
      for (int i = 0; i < 2; ++i) {
        int m = wave * 32 + i * 16 + l15;
        int cact = (ks * 4 + q4) ^ (m & 7);
        pa[i] = *(const bf16x8*)(Psm + m * 64 + cact * 8);
      }
#pragma unroll
      for (int dn = 0; dn < 4; ++dn) {
        int dd = dn * 16 + l15;
        int cact = (ks * 4 + q4) ^ (dd & 7);
        vb[dn] = *(const bf16x8*)(Vsm[cur] + dd * 64 + cact * 8);
      }
#pragma unroll
      for (int i = 0; i < 2; ++i)
#pragma unroll
        for (int dn = 0; dn < 4; ++dn)
          acc[i][dn] = __builtin_amdgcn_mfma_f32_16x16x32_bf16(pa[i], vb[dn], acc[i][dn], 0, 0, 0);
    }
  }

  // epilogue: reduce row sums once, O /= l, write bf16 [B*N][H*64]
  const int b = bh >> 3, h = bh & 7;
#pragma unroll
  for (int i = 0; i < 2; ++i) {
    float inv[4];
#pragma unroll
    for (int r = 0; r < 4; ++r) {
      float l = suml[i][r];
#pragma unroll
      for (int off = 8; off >= 1; off >>= 1)
        l += __shfl_xor(l, off, 64);
      inv[r] = 1.0f / l;
    }
#pragma unroll
    for (int dn = 0; dn < 4; ++dn) {
#pragma unroll
      for (int r = 0; r < 4; ++r) {
        long row = (long)b * 1024 + nb * 128 + wave * 32 + i * 16 + q4 * 4 + r;
        long col = h * 64 + dn * 16 + l15;
        Ob[row * 512 + col] = bfbits(acc[i][dn][r] * inv[r]);
      }
    }
  }
}

extern "C" void kernel_launch(void* const* d_in, const int* in_sizes, int n_in,
                              void* d_out, int out_size, void* d_ws, size_t ws_size,
                              hipStream_t stream) {
  const float* x   = (const float*)d_in[0];   // [8,1024,512]
  const float* ctx = (const float*)d_in[1];   // [8,1024,512]
  const float* Wq  = (const float*)d_in[2];   // [512,512]
  const float* Wkv = (const float*)d_in[3];   // [512,1024]
  const float* Wo  = (const float*)d_in[4];   // [512,512]
  const float* bo  = (const float*)d_in[5];   // [512]
  float* out = (float*)d_out;

  char* ws = (char*)d_ws;
  unsigned short* Xb   = (unsigned short*)(ws);                 // 8 MB
  unsigned short* Cb   = (unsigned short*)(ws + (8u  << 20));   // 8 MB
  unsigned short* WqT  = (unsigned short*)(ws + (16u << 20));   // 0.5 MB
  unsigned short* WkvT = (unsigned short*)(ws + (17u << 20));   // 1 MB
  unsigned short* WoT  = (unsigned short*)(ws + (19u << 20));   // 0.5 MB
  unsigned short* Qb   = (unsigned short*)(ws + (20u << 20));   // 8 MB
  unsigned short* Kb   = (unsigned short*)(ws + (28u << 20));   // 8 MB
  unsigned short* Vt   = (unsigned short*)(ws + (36u << 20));   // 8 MB
  unsigned short* Ob   = (unsigned short*)(ws + (44u << 20));   // 8 MB  (total 52 MB)

  cvt2_f32_bf16<<<8192, 256, 0, stream>>>(x, ctx, Xb, Cb);
  transpose_cvt3<<<dim3(32, 16, 3), dim3(32, 8), 0, stream>>>(Wq, Wkv, Wo, WqT, WkvT, WoT);

  gemm_bf16<0, 64><<<dim3(4, 128), 256, 0, stream>>>(Xb, WqT, Qb, nullptr, nullptr, nullptr, 8192, 512, 512);
  gemm_bf16<1, 128><<<dim3(8, 64), 256, 0, stream>>>(Cb, WkvT, Kb, Vt, nullptr, nullptr, 8192, 1024, 512);
  attn_kernel<<<dim3(64, 8), 256, 0, stream>>>(Qb, Kb, Vt, Ob);
  gemm_bf16<2, 64><<<dim3(4, 128), 256, 0, stream>>>(Ob, WoT, nullptr, nullptr, out, bo, 8192, 512, 512);
}

// Round 3
// 162.409 us; speedup vs baseline: 1.3735x; 1.0714x over previous
//
#include <hip/hip_runtime.h>
#include <stdint.h>

#define LOG2E 1.44269504088896340736f
#define QSCALE (0.125f * LOG2E)   // dim_head^-0.5 folded with log2(e) for exp2-domain softmax

typedef __bf16 bf16x8 __attribute__((ext_vector_type(8)));
typedef float floatx4 __attribute__((ext_vector_type(4)));

__device__ __forceinline__ unsigned short bfbits(float f) {
  __bf16 h = (__bf16)f;
  return __builtin_bit_cast(unsigned short, h);
}

__device__ __forceinline__ float fast_exp2(float x) {
#if __has_builtin(__builtin_amdgcn_exp2f)
  return __builtin_amdgcn_exp2f(x);
#else
  return exp2f(x);
#endif
}

__device__ __forceinline__ void gl2lds16(const void* g, void* l) {
  __builtin_amdgcn_global_load_lds((const __attribute__((address_space(1))) void*)g,
                                   (__attribute__((address_space(3))) void*)l, 16, 0, 0);
}

// ---------------- prep: fp32->bf16 cvt of x/ctx + transpose-cvt of Wq/Wkv/Wo ----------------
// blocks 0..8191: cvt (0..4095 x, 4096..8191 ctx). blocks 8192..9215: 32x32 transpose tiles.
__global__ __launch_bounds__(256)
void prep_kernel(const float* __restrict__ x, const float* __restrict__ ctx,
                 const float* __restrict__ Wq, const float* __restrict__ Wkv,
                 const float* __restrict__ Wo,
                 unsigned short* __restrict__ Xb, unsigned short* __restrict__ Cb,
                 unsigned short* __restrict__ WqT, unsigned short* __restrict__ WkvT,
                 unsigned short* __restrict__ WoT) {
  int blk = blockIdx.x;
  int tid = threadIdx.x;
  if (blk < 8192) {
    const float* in = blk < 4096 ? x : ctx;
    unsigned short* out = blk < 4096 ? Xb : Cb;
    int i = (((blk & 4095) * 256) + tid) * 4;
    float4 v = *(const float4*)(in + i);
    unsigned long long pk = (unsigned long long)bfbits(v.x)
                          | ((unsigned long long)bfbits(v.y) << 16)
                          | ((unsigned long long)bfbits(v.z) << 32)
                          | ((unsigned long long)bfbits(v.w) << 48);
    *(unsigned long long*)(out + i) = pk;
  } else {
    __shared__ float tile[32][33];
    int t = blk - 8192;  // 0..1023
    const float* in; unsigned short* out; int N; int tb;
    if (t < 256)      { in = Wq;  out = WqT;  N = 512;  tb = t; }
    else if (t < 768) { in = Wkv; out = WkvT; N = 1024; tb = t - 256; }
    else              { in = Wo;  out = WoT;  N = 512;  tb = t - 768; }
    const int K = 512;
    int nbx = N / 32;
    int n0 = (tb % nbx) * 32, k0 = (tb / nbx) * 32;
    int tx = tid & 31, ty = tid >> 5;
#pragma unroll
    for (int r = ty; r < 32; r += 8)
      tile[r][tx] = in[(long)(k0 + r) * N + n0 + tx];
    __syncthreads();
#pragma unroll
    for (int r = ty; r < 32; r += 8)
      out[(long)(n0 + r) * K + k0 + tx] = bfbits(tile[tx][r]);
  }
}

// ---------------- proj: fused Q-proj and KV-proj GEMMs, 64x128x32 tiles ----------------
// blocks 0..511: Q = Xb * WqT^T -> Qb[b,h,n,d] (scaled). blocks 512..1535: KV = Cb * WkvT^T
//   -> Kb[b,h,m,d] (cols<512) / Vt[b,h,d,m] (cols>=512, 8B-packed stores).
__global__ __launch_bounds__(256)
void proj_gemm(const unsigned short* __restrict__ Xb, const unsigned short* __restrict__ Cb,
               const unsigned short* __restrict__ WqT, const unsigned short* __restrict__ WkvT,
               unsigned short* __restrict__ Qb, unsigned short* __restrict__ Kb,
               unsigned short* __restrict__ Vt) {
  __shared__ unsigned short As[64 * 32];
  __shared__ unsigned short Bs[128 * 32];

  int idx = blockIdx.x;
  const unsigned short* A; const unsigned short* Bt;
  long bm, bn; int role;
  if (idx < 512) { role = 0; A = Xb; Bt = WqT;  bn = (long)(idx & 3) * 128; bm = (long)(idx >> 2) * 64; }
  else { idx -= 512; role = 1; A = Cb; Bt = WkvT; bn = (long)(idx & 7) * 128; bm = (long)(idx >> 3) * 64; }

  const int tid = threadIdx.x;
  const int wave = tid >> 6;
  const int lane = tid & 63;
  const int l15 = lane & 15;
  const int q4 = lane >> 4;
  const int wm = (wave & 1) * 32;
  const int wn = (wave >> 1) * 64;
  const int K = 512;

  floatx4 acc[2][4];
#pragma unroll
  for (int i = 0; i < 2; ++i)
#pragma unroll
    for (int j = 0; j < 4; ++j) { acc[i][j][0]=0.f; acc[i][j][1]=0.f; acc[i][j][2]=0.f; acc[i][j][3]=0.f; }

  for (int k0 = 0; k0 < K; k0 += 32) {
    {
      int r = tid >> 2, kc = tid & 3;
      gl2lds16(A + (bm + r) * (long)K + k0 + kc * 8, (char*)As + tid * 16);
    }
#pragma unroll
    for (int cc = 0; cc < 2; ++cc) {
      int c = cc * 256 + tid;
      int r = c >> 2, kc = c & 3;
      gl2lds16(Bt + (bn + r) * (long)K + k0 + kc * 8, (char*)Bs + c * 16);
    }
    __syncthreads();
    bf16x8 af[2], bfr[4];
#pragma unroll
    for (int i = 0; i < 2; ++i)
      af[i] = *(const bf16x8*)(As + (wm + i * 16 + l15) * 32 + q4 * 8);
#pragma unroll
    for (int j = 0; j < 4; ++j)
      bfr[j] = *(const bf16x8*)(Bs + (wn + j * 16 + l15) * 32 + q4 * 8);
#pragma unroll
    for (int i = 0; i < 2; ++i)
#pragma unroll
      for (int j = 0; j < 4; ++j)
        acc[i][j] = __builtin_amdgcn_mfma_f32_16x16x32_bf16(af[i], bfr[j], acc[i][j], 0, 0, 0);
    __syncthreads();
  }

#pragma unroll
  for (int i = 0; i < 2; ++i) {
#pragma unroll
    for (int j = 0; j < 4; ++j) {
      long col = bn + wn + j * 16 + l15;
      if (role == 1 && col >= 512) {
        // V half: pack 4 consecutive-m bf16 into one 8B store (Vt[b,h,d,m])
        long h = (col - 512) >> 6, d = col & 63;
        long row0 = bm + wm + i * 16 + q4 * 4;
        long b = row0 >> 10, m0 = row0 & 1023;
        unsigned long long pk = (unsigned long long)bfbits(acc[i][j][0])
                              | ((unsigned long long)bfbits(acc[i][j][1]) << 16)
                              | ((unsigned long long)bfbits(acc[i][j][2]) << 32)
                              | ((unsigned long long)bfbits(acc[i][j][3]) << 48);
        *(unsigned long long*)(Vt + ((b * 8 + h) * 64 + d) * 1024 + m0) = pk;
      } else {
        long h = col >> 6, d = col & 63;
#pragma unroll
        for (int r = 0; r < 4; ++r) {
          long row = bm + wm + i * 16 + q4 * 4 + r;   // C/D: row=(lane>>4)*4+reg, col=lane&15
          long b = row >> 10, n = row & 1023;
          float v = acc[i][j][r];
          if (role == 0) Qb[((b * 8 + h) * 1024 + n) * 64 + d] = bfbits(v * QSCALE);
          else           Kb[((b * 8 + h) * 1024 + n) * 64 + d] = bfbits(v);
        }
      }
    }
  }
}

// ---------------- flash attention, S^T formulation ----------------
// grid (64 bh, 16 nb), 256 threads. Each wave: 16 q-rows. KV tiles of 64. LDS 40KB.
// S^T = K·Q^T so the C-frag holds 4 consecutive kv-cols per lane -> packed b64 P writes,
// scalar per-lane row-sum. No max-subtraction (|s|<=~10, exp2 safe in fp32).
__global__ __launch_bounds__(256)
void attn_kernel(const unsigned short* __restrict__ Qb,  // [64][1024][64] (pre-scaled)
                 const unsigned short* __restrict__ Kb,  // [64][1024][64]
                 const unsigned short* __restrict__ Vt,  // [64][64][1024]
                 unsigned short* __restrict__ Ob)        // [8192][512]
{
  __shared__ unsigned short Ksm[2][4096];  // [64 j][64 d], 16B-chunk XOR swizzle
  __shared__ unsigned short Vsm[2][4096];  // [64 d][64 m], 16B-chunk XOR swizzle
  __shared__ unsigned short Psm[64 * 64];  // [64 qrows][64 j], wave-private 16-row bands

  const int tid = threadIdx.x;
  const int wave = tid >> 6;
  const int lane = tid & 63;
  const int l15 = lane & 15;
  const int q4 = lane >> 4;
  const int bh = blockIdx.x;
  const int nb = blockIdx.y;

  // Q B-frags: B[n=l15 (qrow)][k=q4*8+j (d)]
  bf16x8 qf[2];
#pragma unroll
  for (int ks = 0; ks < 2; ++ks)
    qf[ks] = *(const bf16x8*)(Qb + ((long)bh * 1024 + nb * 64 + wave * 16 + l15) * 64 + ks * 32 + q4 * 8);

  floatx4 acc[4];
#pragma unroll
  for (int d = 0; d < 4; ++d) { acc[d][0]=0.f; acc[d][1]=0.f; acc[d][2]=0.f; acc[d][3]=0.f; }
  float suml = 0.0f;

  const unsigned short* Kbase = Kb + (long)bh * 65536;
  const unsigned short* Vbase = Vt + (long)bh * 65536;
  int koff[2], voff[2], lds16[2];
#pragma unroll
  for (int cc = 0; cc < 2; ++cc) {
    int c = cc * 256 + tid;
    int jrow = c >> 3;
    int cact = (c & 7) ^ (jrow & 7);
    koff[cc] = jrow * 64 + cact * 8;
    voff[cc] = jrow * 1024 + cact * 8;
    lds16[cc] = c * 16;
  }
#pragma unroll
  for (int cc = 0; cc < 2; ++cc) {
    gl2lds16(Kbase + koff[cc], (char*)Ksm[0] + lds16[cc]);
    gl2lds16(Vbase + voff[cc], (char*)Vsm[0] + lds16[cc]);
  }

  const int prow = wave * 16 + l15;

  for (int t = 0; t < 16; ++t) {
    __syncthreads();
    const int cur = t & 1;
    if (t + 1 < 16) {
      const int nxt = cur ^ 1;
#pragma unroll
      for (int cc = 0; cc < 2; ++cc) {
        gl2lds16(Kbase + (t + 1) * 4096 + koff[cc], (char*)Ksm[nxt] + lds16[cc]);
        gl2lds16(Vbase + (t + 1) * 64 + voff[cc], (char*)Vsm[nxt] + lds16[cc]);
      }
    }

    // S^T = K Q^T : C col=l15 -> qrow, row=q4*4+r -> kv j
    floatx4 st[4];
#pragma unroll
    for (int jn = 0; jn < 4; ++jn) { st[jn][0]=0.f; st[jn][1]=0.f; st[jn][2]=0.f; st[jn][3]=0.f; }
#pragma unroll
    for (int ks = 0; ks < 2; ++ks) {
      bf16x8 kfr[4];
#pragma unroll
      for (int jn = 0; jn < 4; ++jn) {
        int j = jn * 16 + l15;
        int cact = (ks * 4 + q4) ^ (j & 7);
        kfr[jn] = *(const bf16x8*)(Ksm[cur] + j * 64 + cact * 8);
      }
#pragma unroll
      for (int jn = 0; jn < 4; ++jn)
        st[jn] = __builtin_amdgcn_mfma_f32_16x16x32_bf16(kfr[jn], qf[ks], st[jn], 0, 0, 0);
    }

    // p = exp2(s); per-lane row-sum partial; packed b64 P write (4 consecutive kv-cols)
#pragma unroll
    for (int jn = 0; jn < 4; ++jn) {
      float p0 = fast_exp2(st[jn][0]);
      float p1 = fast_exp2(st[jn][1]);
      float p2 = fast_exp2(st[jn][2]);
      float p3 = fast_exp2(st[jn][3]);
      suml += (p0 + p1) + (p2 + p3);
      unsigned long long pk = (unsigned long long)bfbits(p0)
                            | ((unsigned long long)bfbits(p1) << 16)
                            | ((unsigned long long)bfbits(p2) << 32)
                            | ((unsigned long long)bfbits(p3) << 48);
      int ch8 = (jn * 2 + (q4 >> 1)) ^ (prow & 7);
      *(unsigned long long*)(Psm + prow * 64 + ch8 * 8 + (q4 & 1) * 4) = pk;
    }
    __asm__ volatile("s_waitcnt lgkmcnt(0)" ::: "memory");

    // O += P V : A-frag from Psm (m=qrow), B-frag from Vsm (n=d)
#pragma unroll
    for (int ks = 0; ks < 2; ++ks) {
      bf16x8 pa = *(const bf16x8*)(Psm + prow * 64 + (((ks * 4 + q4) ^ (prow & 7)) * 8));
      bf16x8 vb[4];
#pragma unroll
      for (int dn = 0; dn < 4; ++dn) {
        int dd = dn * 16 + l15;
        int cact = (ks * 4 + q4) ^ (dd & 7);
        vb[dn] = *(const bf16x8*)(Vsm[cur] + dd * 64 + cact * 8);
      }
#pragma unroll
      for (int dn = 0; dn < 4; ++dn)
        acc[dn] = __builtin_amdgcn_mfma_f32_16x16x32_bf16(pa, vb[dn], acc[dn], 0, 0, 0);
    }
  }

  // reduce row sums across quads (row = l15), fetch inv for this lane's acc rows via bpermute
  float l = suml;
  l += __shfl_xor(l, 16, 64);
  l += __shfl_xor(l, 32, 64);
  float inv = 1.0f / l;
  float invr[4];
#pragma unroll
  for (int r = 0; r < 4; ++r) invr[r] = __shfl(inv, q4 * 4 + r, 64);

  const int b = bh >> 3, h = bh & 7;
#pragma unroll
  for (int dn = 0; dn < 4; ++dn) {
#pragma unroll
    for (int r = 0; r < 4; ++r) {
      long row = (long)b * 1024 + nb * 64 + wave * 16 + q4 * 4 + r;  // O C-frag: row=q4*4+r (qrow)
      long col = h * 64 + dn * 16 + l15;                              //           col=l15 (d)
      Ob[row * 512 + col] = bfbits(acc[dn][r] * invr[r]);
    }
  }
}

// ---------------- final GEMM: out = Ob * WoT^T + bias, fp32 out ----------------
__global__ __launch_bounds__(256)
void out_gemm(const unsigned short* __restrict__ A,   // Ob [8192][512]
              const unsigned short* __restrict__ Bt,  // WoT [512][512]
              float* __restrict__ outF, const float* __restrict__ bias) {
  __shared__ unsigned short As[64 * 32];
  __shared__ unsigned short Bs[128 * 32];

  const int tid = threadIdx.x;
  const int wave = tid >> 6;
  const int lane = tid & 63;
  const int l15 = lane & 15;
  const int q4 = lane >> 4;
  const int wm = (wave & 1) * 32;
  const int wn = (wave >> 1) * 64;
  const long bm = (long)blockIdx.y * 64;
  const long bn = (long)blockIdx.x * 128;
  const int K = 512, N = 512;

  floatx4 acc[2][4];
#pragma unroll
  for (int i = 0; i < 2; ++i)
#pragma unroll
    for (int j = 0; j < 4; ++j) { acc[i][j][0]=0.f; acc[i][j][1]=0.f; acc[i][j][2]=0.f; acc[i][j][3]=0.f; }

  for (int k0 = 0; k0 < K; k0 += 32) {
    {
      int r = tid >> 2, kc = tid & 3;
      gl2lds16(A + (bm + r) * (long)K + k0 + kc * 8, (char*)As + tid * 16);
    }
#pragma unroll
    for (int cc = 0; cc < 2; ++cc) {
      int c = cc * 256 + tid;
      int r = c >> 2, kc = c & 3;
      gl2lds16(Bt + (bn + r) * (long)K + k0 + kc * 8, (char*)Bs + c * 16);
    }
    __syncthreads();
    bf16x8 af[2], bfr[4];
#pragma unroll
    for (int i = 0; i < 2; ++i)
      af[i] = *(const bf16x8*)(As + (wm + i * 16 + l15) * 32 + q4 * 8);
#pragma unroll
    for (int j = 0; j < 4; ++j)
      bfr[j] = *(const bf16x8*)(Bs + (wn + j * 16 + l15) * 32 + q4 * 8);
#pragma unroll
    for (int i = 0; i < 2; ++i)
#pragma unroll
      for (int j = 0; j < 4; ++j)
        acc[i][j] = __builtin_amdgcn_mfma_f32_16x16x32_bf16(af[i], bfr[j], acc[i][j], 0, 0, 0);
    __syncthreads();
  }

#pragma unroll
  for (int i = 0; i < 2; ++i) {
#pragma unroll
    for (int j = 0; j < 4; ++j) {
      long col = bn + wn + j * 16 + l15;
      float bv = bias[col];
#pragma unroll
      for (int r = 0; r < 4; ++r) {
        long row = bm + wm + i * 16 + q4 * 4 + r;
        outF[row * (long)N + col] = acc[i][j][r] + bv;
      }
    }
  }
}

extern "C" void kernel_launch(void* const* d_in, const int* in_sizes, int n_in,
                              void* d_out, int out_size, void* d_ws, size_t ws_size,
                              hipStream_t stream) {
  const float* x   = (const float*)d_in[0];   // [8,1024,512]
  const float* ctx = (const float*)d_in[1];   // [8,1024,512]
  const float* Wq  = (const float*)d_in[2];   // [512,512]
  const float* Wkv = (const float*)d_in[3];   // [512,1024]
  const float* Wo  = (const float*)d_in[4];   // [512,512]
  const float* bo  = (const float*)d_in[5];   // [512]
  float* out = (float*)d_out;

  char* ws = (char*)d_ws;
  unsigned short* Xb   = (unsigned short*)(ws);                 // 8 MB
  unsigned short* Cb   = (unsigned short*)(ws + (8u  << 20));   // 8 MB
  unsigned short* WqT  = (unsigned short*)(ws + (16u << 20));   // 0.5 MB
  unsigned short* WkvT = (unsigned short*)(ws + (17u << 20));   // 1 MB
  unsigned short* WoT  = (unsigned short*)(ws + (19u << 20));   // 0.5 MB
  unsigned short* Qb   = (unsigned short*)(ws + (20u << 20));   // 8 MB
  unsigned short* Kb   = (unsigned short*)(ws + (28u << 20));   // 8 MB
  unsigned short* Vt   = (unsigned short*)(ws + (36u << 20));   // 8 MB
  unsigned short* Ob   = (unsigned short*)(ws + (44u << 20));   // 8 MB  (total 52 MB)

  prep_kernel<<<9216, 256, 0, stream>>>(x, ctx, Wq, Wkv, Wo, Xb, Cb, WqT, WkvT, WoT);
  proj_gemm<<<1536, 256, 0, stream>>>(Xb, Cb, WqT, WkvT, Qb, Kb, Vt);
  attn_kernel<<<dim3(64, 16), 256, 0, stream>>>(Qb, Kb, Vt, Ob);
  out_gemm<<<dim3(4, 128), 256, 0, stream>>>(Ob, WoT, out, bo);
}

// Round 4
// 157.221 us; speedup vs baseline: 1.4188x; 1.0330x over previous
//
#include <hip/hip_runtime.h>
#include <stdint.h>

#define LOG2E 1.44269504088896340736f
#define QSCALE (0.125f * LOG2E)   // dim_head^-0.5 folded with log2(e) for exp2-domain softmax

typedef __bf16 bf16x8 __attribute__((ext_vector_type(8)));
typedef float floatx4 __attribute__((ext_vector_type(4)));

__device__ __forceinline__ unsigned short bfbits(float f) {
  __bf16 h = (__bf16)f;
  return __builtin_bit_cast(unsigned short, h);
}

__device__ __forceinline__ float fast_exp2(float x) {
#if __has_builtin(__builtin_amdgcn_exp2f)
  return __builtin_amdgcn_exp2f(x);
#else
  return exp2f(x);
#endif
}

__device__ __forceinline__ void gl2lds16(const void* g, void* l) {
  __builtin_amdgcn_global_load_lds((const __attribute__((address_space(1))) void*)g,
                                   (__attribute__((address_space(3))) void*)l, 16, 0, 0);
}

// ---------------- prep: fp32->bf16 cvt of x/ctx + transpose-cvt of Wq/Wkv/Wo ----------------
__global__ __launch_bounds__(256)
void prep_kernel(const float* __restrict__ x, const float* __restrict__ ctx,
                 const float* __restrict__ Wq, const float* __restrict__ Wkv,
                 const float* __restrict__ Wo,
                 unsigned short* __restrict__ Xb, unsigned short* __restrict__ Cb,
                 unsigned short* __restrict__ WqT, unsigned short* __restrict__ WkvT,
                 unsigned short* __restrict__ WoT) {
  int blk = blockIdx.x;
  int tid = threadIdx.x;
  if (blk < 8192) {
    const float* in = blk < 4096 ? x : ctx;
    unsigned short* out = blk < 4096 ? Xb : Cb;
    int i = (((blk & 4095) * 256) + tid) * 4;
    float4 v = *(const float4*)(in + i);
    unsigned long long pk = (unsigned long long)bfbits(v.x)
                          | ((unsigned long long)bfbits(v.y) << 16)
                          | ((unsigned long long)bfbits(v.z) << 32)
                          | ((unsigned long long)bfbits(v.w) << 48);
    *(unsigned long long*)(out + i) = pk;
  } else {
    __shared__ float tile[32][33];
    int t = blk - 8192;  // 0..1023
    const float* in; unsigned short* out; int N; int tb;
    if (t < 256)      { in = Wq;  out = WqT;  N = 512;  tb = t; }
    else if (t < 768) { in = Wkv; out = WkvT; N = 1024; tb = t - 256; }
    else              { in = Wo;  out = WoT;  N = 512;  tb = t - 768; }
    const int K = 512;
    int nbx = N / 32;
    int n0 = (tb % nbx) * 32, k0 = (tb / nbx) * 32;
    int tx = tid & 31, ty = tid >> 5;
#pragma unroll
    for (int r = ty; r < 32; r += 8)
      tile[r][tx] = in[(long)(k0 + r) * N + n0 + tx];
    __syncthreads();
#pragma unroll
    for (int r = ty; r < 32; r += 8)
      out[(long)(n0 + r) * K + k0 + tx] = bfbits(tile[tx][r]);
  }
}

// ---------------- proj: fused Q-proj and KV-proj GEMMs, 128x128x32 tiles ----------------
// blocks 0..255: Q = Xb * WqT^T -> Qb[b,h,n,d] (scaled).
// blocks 256..767: KV = Cb * WkvT^T -> Kb[b,h,m,d] (bn<512) / Vt[b,h,d,m] (bn>=512, 8B packed).
__global__ __launch_bounds__(256)
void proj_gemm(const unsigned short* __restrict__ Xb, const unsigned short* __restrict__ Cb,
               const unsigned short* __restrict__ WqT, const unsigned short* __restrict__ WkvT,
               unsigned short* __restrict__ Qb, unsigned short* __restrict__ Kb,
               unsigned short* __restrict__ Vt) {
  __shared__ unsigned short As[128 * 32];
  __shared__ unsigned short Bs[128 * 32];

  int idx = blockIdx.x;
  const unsigned short* A; const unsigned short* Bt;
  long bm, bn; int role;
  if (idx < 256) { role = 0; A = Xb; Bt = WqT;  bn = (long)(idx & 3) * 128; bm = (long)(idx >> 2) * 128; }
  else { idx -= 256; role = 1; A = Cb; Bt = WkvT; bn = (long)(idx & 7) * 128; bm = (long)(idx >> 3) * 128; }

  const int tid = threadIdx.x;
  const int wave = tid >> 6;
  const int lane = tid & 63;
  const int l15 = lane & 15;
  const int q4 = lane >> 4;
  const int wm = (wave & 1) * 64;
  const int wn = (wave >> 1) * 64;
  const int K = 512;

  floatx4 acc[4][4];
#pragma unroll
  for (int i = 0; i < 4; ++i)
#pragma unroll
    for (int j = 0; j < 4; ++j) { acc[i][j][0]=0.f; acc[i][j][1]=0.f; acc[i][j][2]=0.f; acc[i][j][3]=0.f; }

  for (int k0 = 0; k0 < K; k0 += 32) {
#pragma unroll
    for (int cc = 0; cc < 2; ++cc) {
      int c = cc * 256 + tid;
      int r = c >> 2, kc = c & 3;
      gl2lds16(A + (bm + r) * (long)K + k0 + kc * 8, (char*)As + c * 16);
      gl2lds16(Bt + (bn + r) * (long)K + k0 + kc * 8, (char*)Bs + c * 16);
    }
    __syncthreads();
    bf16x8 af[4], bfr[4];
#pragma unroll
    for (int i = 0; i < 4; ++i)
      af[i] = *(const bf16x8*)(As + (wm + i * 16 + l15) * 32 + q4 * 8);
#pragma unroll
    for (int j = 0; j < 4; ++j)
      bfr[j] = *(const bf16x8*)(Bs + (wn + j * 16 + l15) * 32 + q4 * 8);
#pragma unroll
    for (int i = 0; i < 4; ++i)
#pragma unroll
      for (int j = 0; j < 4; ++j)
        acc[i][j] = __builtin_amdgcn_mfma_f32_16x16x32_bf16(af[i], bfr[j], acc[i][j], 0, 0, 0);
    __syncthreads();
  }

  const bool vrole = (role == 1) && (bn >= 512);
#pragma unroll
  for (int i = 0; i < 4; ++i) {
#pragma unroll
    for (int j = 0; j < 4; ++j) {
      long col = bn + wn + j * 16 + l15;
      if (vrole) {
        // V half: pack 4 consecutive-m bf16 into one 8B store (Vt[b,h,d,m])
        long h = (col - 512) >> 6, d = col & 63;
        long row0 = bm + wm + i * 16 + q4 * 4;
        long b = row0 >> 10, m0 = row0 & 1023;
        unsigned long long pk = (unsigned long long)bfbits(acc[i][j][0])
                              | ((unsigned long long)bfbits(acc[i][j][1]) << 16)
                              | ((unsigned long long)bfbits(acc[i][j][2]) << 32)
                              | ((unsigned long long)bfbits(acc[i][j][3]) << 48);
        *(unsigned long long*)(Vt + ((b * 8 + h) * 64 + d) * 1024 + m0) = pk;
      } else {
        long h = col >> 6, d = col & 63;
#pragma unroll
        for (int r = 0; r < 4; ++r) {
          long row = bm + wm + i * 16 + q4 * 4 + r;   // C/D: row=(lane>>4)*4+reg, col=lane&15
          long b = row >> 10, n = row & 1023;
          float v = acc[i][j][r];
          if (role == 0) Qb[((b * 8 + h) * 1024 + n) * 64 + d] = bfbits(v * QSCALE);
          else           Kb[((b * 8 + h) * 1024 + n) * 64 + d] = bfbits(v);
        }
      }
    }
  }
}

// ---------------- flash attention, S^T formulation ----------------
// grid (64 bh, 16 nb), 256 threads. Each wave: 16 q-rows. KV tiles of 64. LDS 40KB.
__global__ __launch_bounds__(256)
void attn_kernel(const unsigned short* __restrict__ Qb,  // [64][1024][64] (pre-scaled)
                 const unsigned short* __restrict__ Kb,  // [64][1024][64]
                 const unsigned short* __restrict__ Vt,  // [64][64][1024]
                 unsigned short* __restrict__ Ob)        // [8192][512]
{
  __shared__ unsigned short Ksm[2][4096];  // [64 j][64 d], 16B-chunk XOR swizzle
  __shared__ unsigned short Vsm[2][4096];  // [64 d][64 m], 16B-chunk XOR swizzle
  __shared__ unsigned short Psm[64 * 64];  // [64 qrows][64 j], wave-private 16-row bands

  const int tid = threadIdx.x;
  const int wave = tid >> 6;
  const int lane = tid & 63;
  const int l15 = lane & 15;
  const int q4 = lane >> 4;
  const int bh = blockIdx.x;
  const int nb = blockIdx.y;

  // Q B-frags: B[n=l15 (qrow)][k=q4*8+j (d)]
  bf16x8 qf[2];
#pragma unroll
  for (int ks = 0; ks < 2; ++ks)
    qf[ks] = *(const bf16x8*)(Qb + ((long)bh * 1024 + nb * 64 + wave * 16 + l15) * 64 + ks * 32 + q4 * 8);

  floatx4 acc[4];
#pragma unroll
  for (int d = 0; d < 4; ++d) { acc[d][0]=0.f; acc[d][1]=0.f; acc[d][2]=0.f; acc[d][3]=0.f; }
  float suml = 0.0f;

  const unsigned short* Kbase = Kb + (long)bh * 65536;
  const unsigned short* Vbase = Vt + (long)bh * 65536;
  int koff[2], voff[2], lds16[2];
#pragma unroll
  for (int cc = 0; cc < 2; ++cc) {
    int c = cc * 256 + tid;
    int jrow = c >> 3;
    int cact = (c & 7) ^ (jrow & 7);
    koff[cc] = jrow * 64 + cact * 8;
    voff[cc] = jrow * 1024 + cact * 8;
    lds16[cc] = c * 16;
  }
#pragma unroll
  for (int cc = 0; cc < 2; ++cc) {
    gl2lds16(Kbase + koff[cc], (char*)Ksm[0] + lds16[cc]);
    gl2lds16(Vbase + voff[cc], (char*)Vsm[0] + lds16[cc]);
  }

  const int prow = wave * 16 + l15;

  for (int t = 0; t < 16; ++t) {
    __syncthreads();
    const int cur = t & 1;
    if (t + 1 < 16) {
      const int nxt = cur ^ 1;
#pragma unroll
      for (int cc = 0; cc < 2; ++cc) {
        gl2lds16(Kbase + (t + 1) * 4096 + koff[cc], (char*)Ksm[nxt] + lds16[cc]);
        gl2lds16(Vbase + (t + 1) * 64 + voff[cc], (char*)Vsm[nxt] + lds16[cc]);
      }
    }

    // S^T = K Q^T : C col=l15 -> qrow, row=q4*4+r -> kv j
    floatx4 st[4];
#pragma unroll
    for (int jn = 0; jn < 4; ++jn) { st[jn][0]=0.f; st[jn][1]=0.f; st[jn][2]=0.f; st[jn][3]=0.f; }
#pragma unroll
    for (int ks = 0; ks < 2; ++ks) {
      bf16x8 kfr[4];
#pragma unroll
      for (int jn = 0; jn < 4; ++jn) {
        int j = jn * 16 + l15;
        int cact = (ks * 4 + q4) ^ (j & 7);
        kfr[jn] = *(const bf16x8*)(Ksm[cur] + j * 64 + cact * 8);
      }
#pragma unroll
      for (int jn = 0; jn < 4; ++jn)
        st[jn] = __builtin_amdgcn_mfma_f32_16x16x32_bf16(kfr[jn], qf[ks], st[jn], 0, 0, 0);
    }

    // p = exp2(s); per-lane row-sum partial; packed b64 P write (4 consecutive kv-cols)
#pragma unroll
    for (int jn = 0; jn < 4; ++jn) {
      float p0 = fast_exp2(st[jn][0]);
      float p1 = fast_exp2(st[jn][1]);
      float p2 = fast_exp2(st[jn][2]);
      float p3 = fast_exp2(st[jn][3]);
      suml += (p0 + p1) + (p2 + p3);
      unsigned long long pk = (unsigned long long)bfbits(p0)
                            | ((unsigned long long)bfbits(p1) << 16)
                            | ((unsigned long long)bfbits(p2) << 32)
                            | ((unsigned long long)bfbits(p3) << 48);
      int ch8 = (jn * 2 + (q4 >> 1)) ^ (prow & 7);
      *(unsigned long long*)(Psm + prow * 64 + ch8 * 8 + (q4 & 1) * 4) = pk;
    }
    __asm__ volatile("s_waitcnt lgkmcnt(0)" ::: "memory");

    // O += P V : A-frag from Psm (m=qrow), B-frag from Vsm (n=d)
#pragma unroll
    for (int ks = 0; ks < 2; ++ks) {
      bf16x8 pa = *(const bf16x8*)(Psm + prow * 64 + (((ks * 4 + q4) ^ (prow & 7)) * 8));
      bf16x8 vb[4];
#pragma unroll
      for (int dn = 0; dn < 4; ++dn) {
        int dd = dn * 16 + l15;
        int cact = (ks * 4 + q4) ^ (dd & 7);
        vb[dn] = *(const bf16x8*)(Vsm[cur] + dd * 64 + cact * 8);
      }
#pragma unroll
      for (int dn = 0; dn < 4; ++dn)
        acc[dn] = __builtin_amdgcn_mfma_f32_16x16x32_bf16(pa, vb[dn], acc[dn], 0, 0, 0);
    }
  }

  // reduce row sums across quads (row = l15), fetch inv for this lane's acc rows
  float l = suml;
  l += __shfl_xor(l, 16, 64);
  l += __shfl_xor(l, 32, 64);
  float inv = 1.0f / l;
  float invr[4];
#pragma unroll
  for (int r = 0; r < 4; ++r) invr[r] = __shfl(inv, q4 * 4 + r, 64);

  const int b = bh >> 3, h = bh & 7;
#pragma unroll
  for (int dn = 0; dn < 4; ++dn) {
#pragma unroll
    for (int r = 0; r < 4; ++r) {
      long row = (long)b * 1024 + nb * 64 + wave * 16 + q4 * 4 + r;  // O C-frag: row=q4*4+r (qrow)
      long col = h * 64 + dn * 16 + l15;                              //           col=l15 (d)
      Ob[row * 512 + col] = bfbits(acc[dn][r] * invr[r]);
    }
  }
}

// ---------------- final GEMM: out = Ob * WoT^T + bias, fp32 out, 64x128x32 ----------------
__global__ __launch_bounds__(256)
void out_gemm(const unsigned short* __restrict__ A,   // Ob [8192][512]
              const unsigned short* __restrict__ Bt,  // WoT [512][512]
              float* __restrict__ outF, const float* __restrict__ bias) {
  __shared__ unsigned short As[64 * 32];
  __shared__ unsigned short Bs[128 * 32];

  const int tid = threadIdx.x;
  const int wave = tid >> 6;
  const int lane = tid & 63;
  const int l15 = lane & 15;
  const int q4 = lane >> 4;
  const int wm = (wave & 1) * 32;
  const int wn = (wave >> 1) * 64;
  const long bm = (long)blockIdx.y * 64;
  const long bn = (long)blockIdx.x * 128;
  const int K = 512, N = 512;

  floatx4 acc[2][4];
#pragma unroll
  for (int i = 0; i < 2; ++i)
#pragma unroll
    for (int j = 0; j < 4; ++j) { acc[i][j][0]=0.f; acc[i][j][1]=0.f; acc[i][j][2]=0.f; acc[i][j][3]=0.f; }

  for (int k0 = 0; k0 < K; k0 += 32) {
    {
      int r = tid >> 2, kc = tid & 3;
      gl2lds16(A + (bm + r) * (long)K + k0 + kc * 8, (char*)As + tid * 16);
    }
#pragma unroll
    for (int cc = 0; cc < 2; ++cc) {
      int c = cc * 256 + tid;
      int r = c >> 2, kc = c & 3;
      gl2lds16(Bt + (bn + r) * (long)K + k0 + kc * 8, (char*)Bs + c * 16);
    }
    __syncthreads();
    bf16x8 af[2], bfr[4];
#pragma unroll
    for (int i = 0; i < 2; ++i)
      af[i] = *(const bf16x8*)(As + (wm + i * 16 + l15) * 32 + q4 * 8);
#pragma unroll
    for (int j = 0; j < 4; ++j)
      bfr[j] = *(const bf16x8*)(Bs + (wn + j * 16 + l15) * 32 + q4 * 8);
#pragma unroll
    for (int i = 0; i < 2; ++i)
#pragma unroll
      for (int j = 0; j < 4; ++j)
        acc[i][j] = __builtin_amdgcn_mfma_f32_16x16x32_bf16(af[i], bfr[j], acc[i][j], 0, 0, 0);
    __syncthreads();
  }

#pragma unroll
  for (int i = 0; i < 2; ++i) {
#pragma unroll
    for (int j = 0; j < 4; ++j) {
      long col = bn + wn + j * 16 + l15;
      float bv = bias[col];
#pragma unroll
      for (int r = 0; r < 4; ++r) {
        long row = bm + wm + i * 16 + q4 * 4 + r;
        outF[row * (long)N + col] = acc[i][j][r] + bv;
      }
    }
  }
}

extern "C" void kernel_launch(void* const* d_in, const int* in_sizes, int n_in,
                              void* d_out, int out_size, void* d_ws, size_t ws_size,
                              hipStream_t stream) {
  const float* x   = (const float*)d_in[0];   // [8,1024,512]
  const float* ctx = (const float*)d_in[1];   // [8,1024,512]
  const float* Wq  = (const float*)d_in[2];   // [512,512]
  const float* Wkv = (const float*)d_in[3];   // [512,1024]
  const float* Wo  = (const float*)d_in[4];   // [512,512]
  const float* bo  = (const float*)d_in[5];   // [512]
  float* out = (float*)d_out;

  char* ws = (char*)d_ws;
  unsigned short* Xb   = (unsigned short*)(ws);                 // 8 MB
  unsigned short* Cb   = (unsigned short*)(ws + (8u  << 20));   // 8 MB
  unsigned short* WqT  = (unsigned short*)(ws + (16u << 20));   // 0.5 MB
  unsigned short* WkvT = (unsigned short*)(ws + (17u << 20));   // 1 MB
  unsigned short* WoT  = (unsigned short*)(ws + (19u << 20));   // 0.5 MB
  unsigned short* Qb   = (unsigned short*)(ws + (20u << 20));   // 8 MB
  unsigned short* Kb   = (unsigned short*)(ws + (28u << 20));   // 8 MB
  unsigned short* Vt   = (unsigned short*)(ws + (36u << 20));   // 8 MB
  unsigned short* Ob   = (unsigned short*)(ws + (44u << 20));   // 8 MB  (total 52 MB)

  prep_kernel<<<9216, 256, 0, stream>>>(x, ctx, Wq, Wkv, Wo, Xb, Cb, WqT, WkvT, WoT);
  proj_gemm<<<768, 256, 0, stream>>>(Xb, Cb, WqT, WkvT, Qb, Kb, Vt);
  attn_kernel<<<dim3(64, 16), 256, 0, stream>>>(Qb, Kb, Vt, Ob);
  out_gemm<<<dim3(4, 128), 256, 0, stream>>>(Ob, WoT, out, bo);
}

// Round 5
// 156.065 us; speedup vs baseline: 1.4293x; 1.0074x over previous
//
#include <hip/hip_runtime.h>
#include <stdint.h>

#define LOG2E 1.44269504088896340736f
#define QSCALE (0.125f * LOG2E)   // dim_head^-0.5 folded with log2(e) for exp2-domain softmax

typedef __bf16 bf16x8 __attribute__((ext_vector_type(8)));
typedef float floatx4 __attribute__((ext_vector_type(4)));

__device__ __forceinline__ unsigned short bfbits(float f) {
  __bf16 h = (__bf16)f;
  return __builtin_bit_cast(unsigned short, h);
}

__device__ __forceinline__ float fast_exp2(float x) {
#if __has_builtin(__builtin_amdgcn_exp2f)
  return __builtin_amdgcn_exp2f(x);
#else
  return exp2f(x);
#endif
}

__device__ __forceinline__ void gl2lds16(const void* g, void* l) {
  __builtin_amdgcn_global_load_lds((const __attribute__((address_space(1))) void*)g,
                                   (__attribute__((address_space(3))) void*)l, 16, 0, 0);
}

// ---------------- prep: fp32->bf16 cvt of x/ctx + transpose-cvt of Wq/Wkv/Wo ----------------
__global__ __launch_bounds__(256)
void prep_kernel(const float* __restrict__ x, const float* __restrict__ ctx,
                 const float* __restrict__ Wq, const float* __restrict__ Wkv,
                 const float* __restrict__ Wo,
                 unsigned short* __restrict__ Xb, unsigned short* __restrict__ Cb,
                 unsigned short* __restrict__ WqT, unsigned short* __restrict__ WkvT,
                 unsigned short* __restrict__ WoT) {
  int blk = blockIdx.x;
  int tid = threadIdx.x;
  if (blk < 8192) {
    const float* in = blk < 4096 ? x : ctx;
    unsigned short* out = blk < 4096 ? Xb : Cb;
    int i = (((blk & 4095) * 256) + tid) * 4;
    float4 v = *(const float4*)(in + i);
    unsigned long long pk = (unsigned long long)bfbits(v.x)
                          | ((unsigned long long)bfbits(v.y) << 16)
                          | ((unsigned long long)bfbits(v.z) << 32)
                          | ((unsigned long long)bfbits(v.w) << 48);
    *(unsigned long long*)(out + i) = pk;
  } else {
    __shared__ float tile[32][33];
    int t = blk - 8192;  // 0..1023
    const float* in; unsigned short* out; int N; int tb;
    if (t < 256)      { in = Wq;  out = WqT;  N = 512;  tb = t; }
    else if (t < 768) { in = Wkv; out = WkvT; N = 1024; tb = t - 256; }
    else              { in = Wo;  out = WoT;  N = 512;  tb = t - 768; }
    const int K = 512;
    int nbx = N / 32;
    int n0 = (tb % nbx) * 32, k0 = (tb / nbx) * 32;
    int tx = tid & 31, ty = tid >> 5;
#pragma unroll
    for (int r = ty; r < 32; r += 8)
      tile[r][tx] = in[(long)(k0 + r) * N + n0 + tx];
    __syncthreads();
#pragma unroll
    for (int r = ty; r < 32; r += 8)
      out[(long)(n0 + r) * K + k0 + tx] = bfbits(tile[tx][r]);
  }
}

// ---------------- proj: fused Q-proj and KV-proj GEMMs, 128x128x32 tiles ----------------
__global__ __launch_bounds__(256)
void proj_gemm(const unsigned short* __restrict__ Xb, const unsigned short* __restrict__ Cb,
               const unsigned short* __restrict__ WqT, const unsigned short* __restrict__ WkvT,
               unsigned short* __restrict__ Qb, unsigned short* __restrict__ Kb,
               unsigned short* __restrict__ Vt) {
  __shared__ unsigned short As[128 * 32];
  __shared__ unsigned short Bs[128 * 32];

  int idx = blockIdx.x;
  const unsigned short* A; const unsigned short* Bt;
  long bm, bn; int role;
  if (idx < 256) { role = 0; A = Xb; Bt = WqT;  bn = (long)(idx & 3) * 128; bm = (long)(idx >> 2) * 128; }
  else { idx -= 256; role = 1; A = Cb; Bt = WkvT; bn = (long)(idx & 7) * 128; bm = (long)(idx >> 3) * 128; }

  const int tid = threadIdx.x;
  const int wave = tid >> 6;
  const int lane = tid & 63;
  const int l15 = lane & 15;
  const int q4 = lane >> 4;
  const int wm = (wave & 1) * 64;
  const int wn = (wave >> 1) * 64;
  const int K = 512;

  floatx4 acc[4][4];
#pragma unroll
  for (int i = 0; i < 4; ++i)
#pragma unroll
    for (int j = 0; j < 4; ++j) { acc[i][j][0]=0.f; acc[i][j][1]=0.f; acc[i][j][2]=0.f; acc[i][j][3]=0.f; }

  for (int k0 = 0; k0 < K; k0 += 32) {
#pragma unroll
    for (int cc = 0; cc < 2; ++cc) {
      int c = cc * 256 + tid;
      int r = c >> 2, kc = c & 3;
      gl2lds16(A + (bm + r) * (long)K + k0 + kc * 8, (char*)As + c * 16);
      gl2lds16(Bt + (bn + r) * (long)K + k0 + kc * 8, (char*)Bs + c * 16);
    }
    __syncthreads();
    bf16x8 af[4], bfr[4];
#pragma unroll
    for (int i = 0; i < 4; ++i)
      af[i] = *(const bf16x8*)(As + (wm + i * 16 + l15) * 32 + q4 * 8);
#pragma unroll
    for (int j = 0; j < 4; ++j)
      bfr[j] = *(const bf16x8*)(Bs + (wn + j * 16 + l15) * 32 + q4 * 8);
#pragma unroll
    for (int i = 0; i < 4; ++i)
#pragma unroll
      for (int j = 0; j < 4; ++j)
        acc[i][j] = __builtin_amdgcn_mfma_f32_16x16x32_bf16(af[i], bfr[j], acc[i][j], 0, 0, 0);
    __syncthreads();
  }

  const bool vrole = (role == 1) && (bn >= 512);
#pragma unroll
  for (int i = 0; i < 4; ++i) {
#pragma unroll
    for (int j = 0; j < 4; ++j) {
      long col = bn + wn + j * 16 + l15;
      if (vrole) {
        long h = (col - 512) >> 6, d = col & 63;
        long row0 = bm + wm + i * 16 + q4 * 4;
        long b = row0 >> 10, m0 = row0 & 1023;
        unsigned long long pk = (unsigned long long)bfbits(acc[i][j][0])
                              | ((unsigned long long)bfbits(acc[i][j][1]) << 16)
                              | ((unsigned long long)bfbits(acc[i][j][2]) << 32)
                              | ((unsigned long long)bfbits(acc[i][j][3]) << 48);
        *(unsigned long long*)(Vt + ((b * 8 + h) * 64 + d) * 1024 + m0) = pk;
      } else {
        long h = col >> 6, d = col & 63;
#pragma unroll
        for (int r = 0; r < 4; ++r) {
          long row = bm + wm + i * 16 + q4 * 4 + r;
          long b = row >> 10, n = row & 1023;
          float v = acc[i][j][r];
          if (role == 0) Qb[((b * 8 + h) * 1024 + n) * 64 + d] = bfbits(v * QSCALE);
          else           Kb[((b * 8 + h) * 1024 + n) * 64 + d] = bfbits(v);
        }
      }
    }
  }
}

// ---------------- flash attention: 128 q/block, 32 q/wave, S^T softmax ----------------
// grid (64 bh, 8 nb), 256 threads. KV tiles of 64, double-buffered. LDS 48KB.
// S^T = K·Q^T: C-frag holds 4 consecutive kv per lane -> packed b64 P writes + scalar
// row-sum partials. 32 q-rows/wave restores K/V fragment reuse (20 ds_read per 32 MFMA).
__global__ __launch_bounds__(256)
void attn_kernel(const unsigned short* __restrict__ Qb,  // [64][1024][64] (pre-scaled)
                 const unsigned short* __restrict__ Kb,  // [64][1024][64]
                 const unsigned short* __restrict__ Vt,  // [64][64][1024]
                 unsigned short* __restrict__ Ob)        // [8192][512]
{
  __shared__ unsigned short Ksm[2][4096];  // [64 kv][64 d], 16B-chunk XOR swizzle
  __shared__ unsigned short Vsm[2][4096];  // [64 d][64 m], 16B-chunk XOR swizzle
  __shared__ unsigned short Psm[128 * 64]; // [128 q][64 kv], wave-private 32-row bands

  const int tid = threadIdx.x;
  const int wave = tid >> 6;
  const int lane = tid & 63;
  const int l15 = lane & 15;
  const int q4 = lane >> 4;
  const int bh = blockIdx.x;
  const int nb = blockIdx.y;

  const long qrow0 = (long)bh * 1024 + nb * 128 + wave * 32;

  // Q B-frags: B[n=l15 (qrow)][k=q4*8+j (d)], two 16-row groups
  bf16x8 qf[2][2];
#pragma unroll
  for (int qn = 0; qn < 2; ++qn)
#pragma unroll
    for (int ks = 0; ks < 2; ++ks)
      qf[qn][ks] = *(const bf16x8*)(Qb + (qrow0 + qn * 16 + l15) * 64 + ks * 32 + q4 * 8);

  floatx4 acc[2][4];
#pragma unroll
  for (int i = 0; i < 2; ++i)
#pragma unroll
    for (int d = 0; d < 4; ++d) { acc[i][d][0]=0.f; acc[i][d][1]=0.f; acc[i][d][2]=0.f; acc[i][d][3]=0.f; }
  float suml[2] = {0.0f, 0.0f};

  const unsigned short* Kbase = Kb + (long)bh * 65536;
  const unsigned short* Vbase = Vt + (long)bh * 65536;
  int koff[2], voff[2], lds16[2];
#pragma unroll
  for (int cc = 0; cc < 2; ++cc) {
    int c = cc * 256 + tid;
    int jrow = c >> 3;
    int cact = (c & 7) ^ (jrow & 7);
    koff[cc] = jrow * 64 + cact * 8;
    voff[cc] = jrow * 1024 + cact * 8;
    lds16[cc] = c * 16;
  }
#pragma unroll
  for (int cc = 0; cc < 2; ++cc) {
    gl2lds16(Kbase + koff[cc], (char*)Ksm[0] + lds16[cc]);
    gl2lds16(Vbase + voff[cc], (char*)Vsm[0] + lds16[cc]);
  }

  for (int t = 0; t < 16; ++t) {
    __syncthreads();
    const int cur = t & 1;
    if (t + 1 < 16) {
      const int nxt = cur ^ 1;
#pragma unroll
      for (int cc = 0; cc < 2; ++cc) {
        gl2lds16(Kbase + (t + 1) * 4096 + koff[cc], (char*)Ksm[nxt] + lds16[cc]);
        gl2lds16(Vbase + (t + 1) * 64 + voff[cc], (char*)Vsm[nxt] + lds16[cc]);
      }
    }

    // S^T = K Q^T : for frag (jn,qn): C col=l15 -> q, row=q4*4+r -> kv
    floatx4 st[4][2];
#pragma unroll
    for (int jn = 0; jn < 4; ++jn)
#pragma unroll
      for (int qn = 0; qn < 2; ++qn) { st[jn][qn][0]=0.f; st[jn][qn][1]=0.f; st[jn][qn][2]=0.f; st[jn][qn][3]=0.f; }
#pragma unroll
    for (int ks = 0; ks < 2; ++ks) {
      bf16x8 kfr[4];
#pragma unroll
      for (int jn = 0; jn < 4; ++jn) {
        int j = jn * 16 + l15;
        int cact = (ks * 4 + q4) ^ (j & 7);
        kfr[jn] = *(const bf16x8*)(Ksm[cur] + j * 64 + cact * 8);
      }
#pragma unroll
      for (int jn = 0; jn < 4; ++jn)
#pragma unroll
        for (int qn = 0; qn < 2; ++qn)
          st[jn][qn] = __builtin_amdgcn_mfma_f32_16x16x32_bf16(kfr[jn], qf[qn][ks], st[jn][qn], 0, 0, 0);
    }

    // p = exp2(s); per-lane partial row sums; packed b64 P writes (4 consecutive kv)
#pragma unroll
    for (int qn = 0; qn < 2; ++qn) {
      int prow = wave * 32 + qn * 16 + l15;
#pragma unroll
      for (int jn = 0; jn < 4; ++jn) {
        float p0 = fast_exp2(st[jn][qn][0]);
        float p1 = fast_exp2(st[jn][qn][1]);
        float p2 = fast_exp2(st[jn][qn][2]);
        float p3 = fast_exp2(st[jn][qn][3]);
        suml[qn] += (p0 + p1) + (p2 + p3);
        unsigned long long pk = (unsigned long long)bfbits(p0)
                              | ((unsigned long long)bfbits(p1) << 16)
                              | ((unsigned long long)bfbits(p2) << 32)
                              | ((unsigned long long)bfbits(p3) << 48);
        int ch16 = (jn * 2 + (q4 >> 1)) ^ (prow & 7);
        *(unsigned long long*)(Psm + prow * 64 + ch16 * 8 + (q4 & 1) * 4) = pk;
      }
    }
    __asm__ volatile("s_waitcnt lgkmcnt(0)" ::: "memory");  // P rows are wave-private

    // O += P V : A-frag from Psm (m=q), B-frag from Vsm (n=d)
#pragma unroll
    for (int ks = 0; ks < 2; ++ks) {
      bf16x8 pa[2], vb[4];
#pragma unroll
      for (int i = 0; i < 2; ++i) {
        int m = wave * 32 + i * 16 + l15;
        int cact = (ks * 4 + q4) ^ (m & 7);
        pa[i] = *(const bf16x8*)(Psm + m * 64 + cact * 8);
      }
#pragma unroll
      for (int dn = 0; dn < 4; ++dn) {
        int dd = dn * 16 + l15;
        int cact = (ks * 4 + q4) ^ (dd & 7);
        vb[dn] = *(const bf16x8*)(Vsm[cur] + dd * 64 + cact * 8);
      }
#pragma unroll
      for (int i = 0; i < 2; ++i)
#pragma unroll
        for (int dn = 0; dn < 4; ++dn)
          acc[i][dn] = __builtin_amdgcn_mfma_f32_16x16x32_bf16(pa[i], vb[dn], acc[i][dn], 0, 0, 0);
    }
  }

  // row sums: lanes l15, l15+16, l15+32, l15+48 hold partials for q=qn*16+l15
  float inv[2], invr[2][4];
#pragma unroll
  for (int qn = 0; qn < 2; ++qn) {
    float l = suml[qn];
    l += __shfl_xor(l, 16, 64);
    l += __shfl_xor(l, 32, 64);
    inv[qn] = 1.0f / l;
#pragma unroll
    for (int r = 0; r < 4; ++r) invr[qn][r] = __shfl(inv[qn], q4 * 4 + r, 64);
  }

  const int b = bh >> 3, h = bh & 7;
#pragma unroll
  for (int i = 0; i < 2; ++i) {
#pragma unroll
    for (int dn = 0; dn < 4; ++dn) {
#pragma unroll
      for (int r = 0; r < 4; ++r) {
        long row = (long)b * 1024 + nb * 128 + wave * 32 + i * 16 + q4 * 4 + r;
        long col = h * 64 + dn * 16 + l15;
        Ob[row * 512 + col] = bfbits(acc[i][dn][r] * invr[i][r]);
      }
    }
  }
}

// ---------------- final GEMM: out = Ob * WoT^T + bias, fp32 out, 64x128x32 ----------------
__global__ __launch_bounds__(256)
void out_gemm(const unsigned short* __restrict__ A,   // Ob [8192][512]
              const unsigned short* __restrict__ Bt,  // WoT [512][512]
              float* __restrict__ outF, const float* __restrict__ bias) {
  __shared__ unsigned short As[64 * 32];
  __shared__ unsigned short Bs[128 * 32];

  const int tid = threadIdx.x;
  const int wave = tid >> 6;
  const int lane = tid & 63;
  const int l15 = lane & 15;
  const int q4 = lane >> 4;
  const int wm = (wave & 1) * 32;
  const int wn = (wave >> 1) * 64;
  const long bm = (long)blockIdx.y * 64;
  const long bn = (long)blockIdx.x * 128;
  const int K = 512, N = 512;

  floatx4 acc[2][4];
#pragma unroll
  for (int i = 0; i < 2; ++i)
#pragma unroll
    for (int j = 0; j < 4; ++j) { acc[i][j][0]=0.f; acc[i][j][1]=0.f; acc[i][j][2]=0.f; acc[i][j][3]=0.f; }

  for (int k0 = 0; k0 < K; k0 += 32) {
    {
      int r = tid >> 2, kc = tid & 3;
      gl2lds16(A + (bm + r) * (long)K + k0 + kc * 8, (char*)As + tid * 16);
    }
#pragma unroll
    for (int cc = 0; cc < 2; ++cc) {
      int c = cc * 256 + tid;
      int r = c >> 2, kc = c & 3;
      gl2lds16(Bt + (bn + r) * (long)K + k0 + kc * 8, (char*)Bs + c * 16);
    }
    __syncthreads();
    bf16x8 af[2], bfr[4];
#pragma unroll
    for (int i = 0; i < 2; ++i)
      af[i] = *(const bf16x8*)(As + (wm + i * 16 + l15) * 32 + q4 * 8);
#pragma unroll
    for (int j = 0; j < 4; ++j)
      bfr[j] = *(const bf16x8*)(Bs + (wn + j * 16 + l15) * 32 + q4 * 8);
#pragma unroll
    for (int i = 0; i < 2; ++i)
#pragma unroll
      for (int j = 0; j < 4; ++j)
        acc[i][j] = __builtin_amdgcn_mfma_f32_16x16x32_bf16(af[i], bfr[j], acc[i][j], 0, 0, 0);
    __syncthreads();
  }

#pragma unroll
  for (int i = 0; i < 2; ++i) {
#pragma unroll
    for (int j = 0; j < 4; ++j) {
      long col = bn + wn + j * 16 + l15;
      float bv = bias[col];
#pragma unroll
      for (int r = 0; r < 4; ++r) {
        long row = bm + wm + i * 16 + q4 * 4 + r;
        outF[row * (long)N + col] = acc[i][j][r] + bv;
      }
    }
  }
}

extern "C" void kernel_launch(void* const* d_in, const int* in_sizes, int n_in,
                              void* d_out, int out_size, void* d_ws, size_t ws_size,
                              hipStream_t stream) {
  const float* x   = (const float*)d_in[0];   // [8,1024,512]
  const float* ctx = (const float*)d_in[1];   // [8,1024,512]
  const float* Wq  = (const float*)d_in[2];   // [512,512]
  const float* Wkv = (const float*)d_in[3];   // [512,1024]
  const float* Wo  = (const float*)d_in[4];   // [512,512]
  const float* bo  = (const float*)d_in[5];   // [512]
  float* out = (float*)d_out;

  char* ws = (char*)d_ws;
  unsigned short* Xb   = (unsigned short*)(ws);                 // 8 MB
  unsigned short* Cb   = (unsigned short*)(ws + (8u  << 20));   // 8 MB
  unsigned short* WqT  = (unsigned short*)(ws + (16u << 20));   // 0.5 MB
  unsigned short* WkvT = (unsigned short*)(ws + (17u << 20));   // 1 MB
  unsigned short* WoT  = (unsigned short*)(ws + (19u << 20));   // 0.5 MB
  unsigned short* Qb   = (unsigned short*)(ws + (20u << 20));   // 8 MB
  unsigned short* Kb   = (unsigned short*)(ws + (28u << 20));   // 8 MB
  unsigned short* Vt   = (unsigned short*)(ws + (36u << 20));   // 8 MB
  unsigned short* Ob   = (unsigned short*)(ws + (44u << 20));   // 8 MB  (total 52 MB)

  prep_kernel<<<9216, 256, 0, stream>>>(x, ctx, Wq, Wkv, Wo, Xb, Cb, WqT, WkvT, WoT);
  proj_gemm<<<768, 256, 0, stream>>>(Xb, Cb, WqT, WkvT, Qb, Kb, Vt);
  attn_kernel<<<dim3(64, 8), 256, 0, stream>>>(Qb, Kb, Vt, Ob);
  out_gemm<<<dim3(4, 128), 256, 0, stream>>>(Ob, WoT, out, bo);
}